// Round 1
// 703.517 us; speedup vs baseline: 1.0090x; 1.0090x over previous
//
#include <hip/hip_runtime.h>
#include <cmath>

#define TC_H 256
#define TC_W 256
#define TC_B 32
#define TC_C 64
#define TC_BC (TC_B * TC_C)

__device__ __forceinline__ float wredf(float v) {
    v += __shfl_xor(v, 32, 64);
    v += __shfl_xor(v, 16, 64);
    v += __shfl_xor(v, 8, 64);
    v += __shfl_xor(v, 4, 64);
    v += __shfl_xor(v, 2, 64);
    v += __shfl_xor(v, 1, 64);
    return v;
}

__device__ __forceinline__ float wmaxf_(float v) {
    v = fmaxf(v, __shfl_xor(v, 32, 64));
    v = fmaxf(v, __shfl_xor(v, 16, 64));
    v = fmaxf(v, __shfl_xor(v, 8, 64));
    v = fmaxf(v, __shfl_xor(v, 4, 64));
    v = fmaxf(v, __shfl_xor(v, 2, 64));
    v = fmaxf(v, __shfl_xor(v, 1, 64));
    return v;
}

// Register-resident row step: vertical 3-row max/min per column, horizontal
// 3-col max/min via cross-lane shuffles (lane l owns cols 4l..4l+3), then
// accumulate A = sum(a), T = sum(a*log2(a)) for both lifetime maps.
__device__ __forceinline__ void row_accum_r(const float4& xm, const float4& xc,
                                            const float4& xp, int lane,
                                            float& A0, float& T0, float& A1, float& T1) {
    float vx0 = fmaxf(fmaxf(xm.x, xp.x), xc.x);
    float vx1 = fmaxf(fmaxf(xm.y, xp.y), xc.y);
    float vx2 = fmaxf(fmaxf(xm.z, xp.z), xc.z);
    float vx3 = fmaxf(fmaxf(xm.w, xp.w), xc.w);
    float vn0 = fminf(fminf(xm.x, xp.x), xc.x);
    float vn1 = fminf(fminf(xm.y, xp.y), xc.y);
    float vn2 = fminf(fminf(xm.z, xp.z), xc.z);
    float vn3 = fminf(fminf(xm.w, xp.w), xc.w);
    // horizontal neighbors across lanes (clamped at image edges)
    float lx = __shfl_up(vx3, 1, 64);   if (lane == 0)  lx = vx0;
    float rx = __shfl_down(vx0, 1, 64); if (lane == 63) rx = vx3;
    float ln_ = __shfl_up(vn3, 1, 64);  if (lane == 0)  ln_ = vn0;
    float rn = __shfl_down(vn0, 1, 64); if (lane == 63) rn = vn3;
    float hm0 = fmaxf(fmaxf(lx,  vx1), vx0);
    float hm1 = fmaxf(fmaxf(vx0, vx2), vx1);
    float hm2 = fmaxf(fmaxf(vx1, vx3), vx2);
    float hm3 = fmaxf(fmaxf(vx2, rx ), vx3);
    float hn0 = fminf(fminf(ln_, vn1), vn0);
    float hn1 = fminf(fminf(vn0, vn2), vn1);
    float hn2 = fminf(fminf(vn1, vn3), vn2);
    float hn3 = fminf(fminf(vn2, rn ), vn3);
    float a;
    a = hm0 - xc.x; A0 += a; T0 += (a > 0.f) ? a * __log2f(a) : 0.f;
    a = hm1 - xc.y; A0 += a; T0 += (a > 0.f) ? a * __log2f(a) : 0.f;
    a = hm2 - xc.z; A0 += a; T0 += (a > 0.f) ? a * __log2f(a) : 0.f;
    a = hm3 - xc.w; A0 += a; T0 += (a > 0.f) ? a * __log2f(a) : 0.f;
    a = xc.x - hn0; A1 += a; T1 += (a > 0.f) ? a * __log2f(a) : 0.f;
    a = xc.y - hn1; A1 += a; T1 += (a > 0.f) ? a * __log2f(a) : 0.f;
    a = xc.z - hn2; A1 += a; T1 += (a > 0.f) ? a * __log2f(a) : 0.f;
    a = xc.w - hn3; A1 += a; T1 += (a > 0.f) ? a * __log2f(a) : 0.f;
}

// One block per (b,c) channel image, 4 waves. Wave wv independently owns the
// 64-row strip [64*wv, 64*wv+64): rolling 3-row register window, depth-3
// prefetch, NO LDS ring, NO main-loop barriers. Halo rows cost 2/64 = 3%
// redundant fetch. Single pass over x (512 MiB -> HBM-bound floor ~85 us).
__global__ __launch_bounds__(256) void topo_pass1(const float* __restrict__ x,
                                                  float* __restrict__ ws) {
    __shared__ float red[4][5];
    const int bc = blockIdx.x;
    const int t = threadIdx.x;
    const int lane = t & 63;
    const int wv = t >> 6;
    const int lc = lane * 4;
    const float* col = x + (size_t)bc * (TC_H * TC_W) + lc;
    const int r0 = wv * 64;

    float zsum = 0.f, A0 = 0.f, T0 = 0.f, A1 = 0.f, T1 = 0.f;

    // window prime: m = row r0-1 (clamped), c = row r0; prefetch rows r0+1, r0+2
    // (r0+1 <= 193 and r0+2 <= 194, so no clamp needed for the primes)
    float4 m  = *(const float4*)(col + (size_t)(wv ? r0 - 1 : 0) * TC_W);
    float4 c  = *(const float4*)(col + (size_t)r0 * TC_W);
    float4 p1 = *(const float4*)(col + (size_t)(r0 + 1) * TC_W);
    float4 p2 = *(const float4*)(col + (size_t)(r0 + 2) * TC_W);

    #pragma unroll 4
    for (int o = 0; o < 64; ++o) {
        // prefetch the row needed as 'p' two iterations from now (clamped at 255;
        // tail duplicates hit L1 and are never mis-used: p1 at step o is always
        // row min(r0+o+1, 255), which is exactly the clamped lower neighbor)
        int nr = r0 + o + 3;
        nr = nr < TC_H ? nr : TC_H - 1;
        float4 nx = *(const float4*)(col + (size_t)nr * TC_W);
        zsum += (c.x + c.y) + (c.z + c.w);
        row_accum_r(m, c, p1, lane, A0, T0, A1, T1);
        m = c; c = p1; p1 = p2; p2 = nx;
    }

    // block reduction of the 5 accumulators
    zsum = wredf(zsum); A0 = wredf(A0); T0 = wredf(T0); A1 = wredf(A1); T1 = wredf(T1);
    if (lane == 0) {
        red[wv][0] = zsum; red[wv][1] = A0; red[wv][2] = T0; red[wv][3] = A1; red[wv][4] = T1;
    }
    __syncthreads();
    if (t == 0) {
        const float LN2 = 0.69314718055994530942f;
        float z  = red[0][0] + red[1][0] + red[2][0] + red[3][0];
        float a0 = red[0][1] + red[1][1] + red[2][1] + red[3][1];
        float t0 = (red[0][2] + red[1][2] + red[2][2] + red[3][2]) * LN2;
        float a1 = red[0][3] + red[1][3] + red[2][3] + red[3][3];
        float t1 = (red[0][4] + red[1][4] + red[2][4] + red[3][4]) * LN2;
        ws[bc]             = z;    // raw sum; divided by H*W in finalize
        ws[TC_BC + bc]     = a0;
        ws[2 * TC_BC + bc] = t0;   // natural-log domain
        ws[3 * TC_BC + bc] = a1;
        ws[4 * TC_BC + bc] = t1;
    }
}

// One block per batch element, 64 threads (= 1 wave, thread c = channel c).
// MLP -> softmax -> analytic entropy -> weighted aggregate -> classifier.
__global__ __launch_bounds__(64) void topo_finalize(
    const float* __restrict__ ws,
    const float* __restrict__ fc1_w, const float* __restrict__ fc1_b,
    const float* __restrict__ fc2_w, const float* __restrict__ fc2_b,
    const float* __restrict__ cls1_w, const float* __restrict__ cls1_b,
    const float* __restrict__ cls2_w, const float* __restrict__ cls2_b,
    float* __restrict__ out) {
    const int b = blockIdx.x;
    const int c = threadIdx.x;   // 0..63
    __shared__ float zsh[TC_C];
    __shared__ float hsh[32];

    float z = ws[b * TC_C + c] * (1.f / (TC_H * TC_W));
    zsh[c] = z;
    __syncthreads();
    if (c < 32) {
        float acc = fc1_b[c];
        #pragma unroll
        for (int k = 0; k < TC_C; ++k) acc += zsh[k] * fc1_w[c * TC_C + k];
        hsh[c] = fmaxf(acc, 0.f);
    }
    __syncthreads();
    float wl = fc2_b[c];
    #pragma unroll
    for (int j = 0; j < 32; ++j) wl += hsh[j] * fc2_w[c * 32 + j];

    // softmax across the 64 channels (one wave)
    float mx = wmaxf_(wl);
    float e = __expf(wl - mx);
    float S = wredf(e);
    float w = e / S;
    out[160 + b * TC_C + c] = w;                       // output 1: w [32,64]

    float sw = wredf(w);
    float wn = w / (sw + 1e-6f);
    float lw = __logf(w);

    // E = [ln(s)*(s-eps) - (w*ln(w)*A + w*T)] / s,  s = w*A + eps
    float A = ws[TC_BC + b * TC_C + c];
    float T = ws[2 * TC_BC + b * TC_C + c];
    float s0 = fmaf(w, A, 1e-12f);
    float E0 = (__logf(s0) * (s0 - 1e-12f) - (w * lw * A + w * T)) / s0;
    A = ws[3 * TC_BC + b * TC_C + c];
    T = ws[4 * TC_BC + b * TC_C + c];
    float s1 = fmaf(w, A, 1e-12f);
    float E1 = (__logf(s1) * (s1 - 1e-12f) - (w * lw * A + w * T)) / s1;

    float f0 = wredf(E0 * wn);   // butterfly: all lanes hold the sums
    float f1 = wredf(E1 * wn);
    if (c == 0) {
        out[2208 + b * 2]     = f0;                    // output 2: f [32,2]
        out[2208 + b * 2 + 1] = f1;
    }

    // classifier: g = relu(f @ cls1_w.T + b) [128], logits = g @ cls2_w.T + b [5]
    float g1 = fmaxf(fmaf(f0, cls1_w[2 * c],        fmaf(f1, cls1_w[2 * c + 1],        cls1_b[c]     )), 0.f);
    const int m2 = c + 64;
    float g2 = fmaxf(fmaf(f0, cls1_w[2 * m2],       fmaf(f1, cls1_w[2 * m2 + 1],       cls1_b[m2]    )), 0.f);
    #pragma unroll
    for (int n = 0; n < 5; ++n) {
        float p = wredf(g1 * cls2_w[n * 128 + c] + g2 * cls2_w[n * 128 + c + 64]);
        if (c == 0) out[b * 5 + n] = p + cls2_b[n];    // output 0: logits [32,5]
    }
}

extern "C" void kernel_launch(void* const* d_in, const int* in_sizes, int n_in,
                              void* d_out, int out_size, void* d_ws, size_t ws_size,
                              hipStream_t stream) {
    const float* x      = (const float*)d_in[0];
    const float* fc1_w  = (const float*)d_in[1];
    const float* fc1_b  = (const float*)d_in[2];
    const float* fc2_w  = (const float*)d_in[3];
    const float* fc2_b  = (const float*)d_in[4];
    const float* cls1_w = (const float*)d_in[5];
    const float* cls1_b = (const float*)d_in[6];
    const float* cls2_w = (const float*)d_in[7];
    const float* cls2_b = (const float*)d_in[8];
    float* out = (float*)d_out;
    float* ws  = (float*)d_ws;   // needs 5 * 2048 * 4 = 40960 bytes

    topo_pass1<<<dim3(TC_BC), dim3(256), 0, stream>>>(x, ws);
    topo_finalize<<<dim3(TC_B), dim3(64), 0, stream>>>(
        ws, fc1_w, fc1_b, fc2_w, fc2_b, cls1_w, cls1_b, cls2_w, cls2_b, out);
}